// Round 1
// baseline (1104.672 us; speedup 1.0000x reference)
//
#include <hip/hip_runtime.h>
#include <math.h>

#define V        8192
#define NTOK     16384          // B*T = 8*2048
#define CWIDTH   32             // columns per bucket
#define NBUCKET  (V / CWIDTH)   // 256
#define JTILE    256            // output columns (j) per scatter block
#define CAP      2048           // max tokens per bucket (mean 64, std ~8 -> huge margin)

// ws layout:
//   [0,    1024) : int counts[NBUCKET]
//   [2048, 2056) : double loss_sum
//   [2056, 2060) : int valid_count
//   [4096, 4096 + NBUCKET*CAP*4) : int bins  (packed (i<<13)|c)   ~2 MiB

__global__ __launch_bounds__(256) void zero_ws_kernel(int* counts, double* loss_sum,
                                                      int* valid_count) {
    counts[threadIdx.x] = 0;
    if (threadIdx.x == 0) { *loss_sum = 0.0; *valid_count = 0; }
}

__global__ __launch_bounds__(256) void bin_kernel(const int* __restrict__ idx,
                                                  int* __restrict__ counts,
                                                  int* __restrict__ bins) {
    int i = blockIdx.x * 256 + threadIdx.x;
    if (i >= NTOK) return;
    int c = idx[i];
    int bucket = c >> 5;
    int pos = atomicAdd(&counts[bucket], 1);
    if (pos < CAP) bins[bucket * CAP + pos] = (i << 13) | c;
}

// One block per (bucket, j-tile). Loads W[j0:j0+256][c0:c0+32] coalesced into
// padded LDS, then for each token in the bucket writes a coalesced 256-float
// logits segment. Each W element is read from HBM exactly once across the grid.
__global__ __launch_bounds__(256) void scatter_kernel(const float* __restrict__ W,
                                                      const float* __restrict__ bias,
                                                      const int* __restrict__ counts,
                                                      const int* __restrict__ bins,
                                                      float* __restrict__ out) {
    __shared__ float lds[JTILE * 33];   // pitch 33 -> bank = (row + col) % 32, conflict-free
    const int tid = threadIdx.x;
    const int bucket = blockIdx.x;
    const int c0 = bucket * CWIDTH;
    const int j0 = blockIdx.y * JTILE;

    // Tile load: 256 threads, 8 float4 each. cg = col-group (8 x float4 = 32 cols).
    const int cg = tid & 7;
    const int rb = tid >> 3;
    #pragma unroll
    for (int m = 0; m < 8; ++m) {
        int r = rb + 32 * m;
        const float4 v = *(const float4*)(&W[(size_t)(j0 + r) * V + c0 + 4 * cg]);
        float* p = &lds[r * 33 + 4 * cg];
        p[0] = v.x; p[1] = v.y; p[2] = v.z; p[3] = v.w;
    }
    const float bj = bias[j0 + tid];
    __syncthreads();

    int n = counts[bucket];
    if (n > CAP) n = CAP;
    const int* mybin = &bins[bucket * CAP];
    for (int t = 0; t < n; ++t) {
        int e = mybin[t];
        int i = e >> 13;
        int c = (e & (V - 1)) - c0;
        out[(size_t)i * V + j0 + tid] = lds[tid * 33 + c] + bj;
    }
}

// One block (256 threads) per token: read its 8192-float logits row, compute
// log-softmax stats with wave-64 shuffle reductions, accumulate NLL.
__global__ __launch_bounds__(256) void loss_kernel(const float* __restrict__ out,
                                                   const int* __restrict__ targets,
                                                   double* __restrict__ loss_sum,
                                                   int* __restrict__ valid_count) {
    const int i = blockIdx.x;
    const int tid = threadIdx.x;
    const float* row = out + (size_t)i * V;

    float4 v[8];
    float lmax = -INFINITY;
    #pragma unroll
    for (int k = 0; k < 8; ++k) {
        v[k] = *(const float4*)(&row[4 * tid + 1024 * k]);
        lmax = fmaxf(lmax, fmaxf(fmaxf(v[k].x, v[k].y), fmaxf(v[k].z, v[k].w)));
    }
    #pragma unroll
    for (int off = 32; off >= 1; off >>= 1)
        lmax = fmaxf(lmax, __shfl_xor(lmax, off, 64));

    __shared__ float smax[4];
    __shared__ float ssum[4];
    const int wave = tid >> 6;
    if ((tid & 63) == 0) smax[wave] = lmax;
    __syncthreads();
    const float m = fmaxf(fmaxf(smax[0], smax[1]), fmaxf(smax[2], smax[3]));

    float lsum = 0.f;
    #pragma unroll
    for (int k = 0; k < 8; ++k)
        lsum += expf(v[k].x - m) + expf(v[k].y - m) +
                expf(v[k].z - m) + expf(v[k].w - m);
    #pragma unroll
    for (int off = 32; off >= 1; off >>= 1)
        lsum += __shfl_xor(lsum, off, 64);
    if ((tid & 63) == 0) ssum[wave] = lsum;
    __syncthreads();

    if (tid == 0) {
        float s = ssum[0] + ssum[1] + ssum[2] + ssum[3];
        int tgt = targets[i];
        if (tgt >= 0) {
            float lt = row[tgt];
            float nll = -(lt - m - logf(s));
            atomicAdd(loss_sum, (double)nll);
            atomicAdd(valid_count, 1);
        }
    }
}

__global__ void finalize_kernel(const double* __restrict__ loss_sum,
                                const int* __restrict__ valid_count,
                                float* __restrict__ out) {
    int c = *valid_count;
    if (c < 1) c = 1;
    out[(size_t)NTOK * V] = (float)(*loss_sum / (double)c);
}

extern "C" void kernel_launch(void* const* d_in, const int* in_sizes, int n_in,
                              void* d_out, int out_size, void* d_ws, size_t ws_size,
                              hipStream_t stream) {
    const int*   idx     = (const int*)d_in[0];
    const int*   targets = (const int*)d_in[1];
    const float* W       = (const float*)d_in[2];
    const float* bias    = (const float*)d_in[3];
    float*       out     = (float*)d_out;

    char* ws = (char*)d_ws;
    int*    counts      = (int*)(ws);
    double* loss_sum    = (double*)(ws + 2048);
    int*    valid_count = (int*)(ws + 2056);
    int*    bins        = (int*)(ws + 4096);

    zero_ws_kernel<<<1, 256, 0, stream>>>(counts, loss_sum, valid_count);
    bin_kernel<<<NTOK / 256, 256, 0, stream>>>(idx, counts, bins);
    dim3 grid3(NBUCKET, V / JTILE);
    scatter_kernel<<<grid3, 256, 0, stream>>>(W, bias, counts, bins, out);
    loss_kernel<<<NTOK, 256, 0, stream>>>(out, targets, loss_sum, valid_count);
    finalize_kernel<<<1, 1, 0, stream>>>(loss_sum, valid_count, out);
}